// Round 10
// baseline (210.209 us; speedup 1.0000x reference)
//
#include <hip/hip_runtime.h>
#include <hip/hip_bf16.h>
#include <math.h>

#define BATCH 2
#define NQ    13125
#define MQ    26250   // BATCH*NQ
#define DM    256
#define NH    8
#define HDIM  32
#define NL    3
#define NP    4
#define NTOK  13125   // value tokens per batch (10000+2500+625)
#define HSTRIDE (MQ * 32)   // per-head plane in head-major vws (tokens x 32ch)

typedef __attribute__((ext_vector_type(8))) short bf16x8;
typedef __attribute__((ext_vector_type(4))) float f32x4;
typedef __attribute__((ext_vector_type(2))) float f32x2;

__device__ __forceinline__ short f2bf(float f) {
    unsigned u = __float_as_uint(f);
    unsigned r = (u + 0x7FFFu + ((u >> 16) & 1u)) >> 16;
    return (short)r;
}
__device__ __forceinline__ float bf2f(unsigned short u) {
    return __uint_as_float((unsigned)u << 16);
}
// hardware packed f32->bf16 (RNE, identical numerics to f2bf)
__device__ __forceinline__ unsigned cvt_pk_bf16(float lo, float hi) {
    unsigned r;
    asm("v_cvt_pk_bf16_f32 %0, %1, %2" : "=v"(r) : "v"(lo), "v"(hi));
    return r;
}

// async global->LDS, 16B per lane. LDS dest must be wave-uniform base + lane*16.
__device__ __forceinline__ void gld_lds16(const short* g, short* l) {
    __builtin_amdgcn_global_load_lds(
        (const __attribute__((address_space(1))) unsigned int*)g,
        (__attribute__((address_space(3))) unsigned int*)l, 16, 0, 0);
}

// ---------------- weight prep: Wt[n][k] bf16 <- W[k][n] fp32, + zero pad (R2-proven) ----------------
// Wt layout: Wt_val rows 0..255 | Wt_off 384 rows (off 0..191, attn 192..287, pad 288..383) | Wt_out
__global__ __launch_bounds__(256) void wprep_kernel(const float* __restrict__ Wv,
                                                    const float* __restrict__ Wo,
                                                    const float* __restrict__ Wa,
                                                    const float* __restrict__ Wu,
                                                    short* __restrict__ Wt)
{
    const int bid = blockIdx.x;
    const int w  = bid >> 8;
    const int Ns[5]   = {256, 192, 96, 256, 96};
    const int Offs[5] = {0, 65536, 114688, 163840, 139264};
    const int N = Ns[w];
    const int flat = (bid & 255) * 256 + threadIdx.x;
    const int n = flat >> 8, k = flat & 255;
    if (n >= N) return;
    if (w == 4) { Wt[139264 + n * 256 + k] = 0; return; }
    const float* W = (w == 0) ? Wv : ((w == 1) ? Wo : ((w == 2) ? Wa : Wu));
    Wt[Offs[w] + n * 256 + k] = f2bf(W[k * N + n]);
}

// ---------------- fused vproj + offs/logits GEMM: 512 thr (8 waves), 2-phase dbuf ----------------
// vws output HEAD-MAJOR: vws[h][token][32ch] (token stride 64B).
__global__ __launch_bounds__(512) void gemm5_kernel(const float* __restrict__ query,
                                                    const float* __restrict__ v0,
                                                    const float* __restrict__ v1,
                                                    const float* __restrict__ v2,
                                                    const short* __restrict__ Wt_val,
                                                    const short* __restrict__ Wt_off,
                                                    const float* __restrict__ b_val,
                                                    const float* __restrict__ b_off,
                                                    const float* __restrict__ b_attn,
                                                    short* __restrict__ vws,
                                                    float* __restrict__ offs,
                                                    float* __restrict__ lgts)
{
    // XCD-locality remap: e = (bid%8)*129 + bid/8 ; (gx, y) = (e/5, e%5)
    const int e = (blockIdx.x & 7) * 129 + (blockIdx.x >> 3);
    if (e >= 1030) return;
    const int y  = e % 5;
    const int m0 = (e / 5) * 128;

    __shared__ short As[2][128 * 32];
    __shared__ short Bs[2][128 * 32];

    const int tid  = threadIdx.x;
    const bool isv = (y < 2);
    const short* Wt = isv ? Wt_val : Wt_off;
    const int n0 = isv ? y * 128 : (y - 2) * 128;

    // ---- per-thread staging coords: row = tid>>2 (0..127), k-quarter qh = tid&3 ----
    const int r  = tid >> 2;
    const int qh = tid & 3;
    const int gm = m0 + r;
    const int gmc = (gm < MQ) ? gm : (MQ - 1);   // clamp: OOB rows read finite garbage
    const float* Arow;
    if (isv) {
        const int b  = gmc / NTOK;
        const int rr = gmc % NTOK;
        if (rr < 10000)      Arow = v0 + (size_t)(b * 10000 + rr) * 256;
        else if (rr < 12500) Arow = v1 + (size_t)(b * 2500 + rr - 10000) * 256;
        else                 Arow = v2 + (size_t)(b * 625 + rr - 12500) * 256;
    } else {
        Arow = query + (size_t)gmc * 256;
    }
    const int pA = (qh ^ ((r >> 1) & 3)) << 3;   // XOR k-granule swizzle (matches read)

    // ---- B staging (glds): same (row, granule) ownership ----
    const int kqs = qh ^ ((r >> 1) & 3);
    const short* gB = Wt + (size_t)(n0 + r) * 256 + kqs * 8;
    short* lB[2] = { Bs[0] + tid * 8, Bs[1] + tid * 8 };

    const int lane = tid & 63;
    const int wave = tid >> 6;
    const int wm   = (wave & 1) * 64;
    const int wn   = (wave >> 1) * 32;
    const int ml   = lane & 15;
    const int kq   = lane >> 4;

    f32x4 acc[4][2] = {};

    // ---- prologue: stage t=0 into buf 0 ----
    {
        gld_lds16(gB, lB[0]);
        const float4 a0 = *(const float4*)(Arow + qh * 8 + 0);
        const float4 a1 = *(const float4*)(Arow + qh * 8 + 4);
        union { bf16x8 v; unsigned u[4]; } t0;
        t0.u[0] = cvt_pk_bf16(a0.x, a0.y); t0.u[1] = cvt_pk_bf16(a0.z, a0.w);
        t0.u[2] = cvt_pk_bf16(a1.x, a1.y); t0.u[3] = cvt_pk_bf16(a1.z, a1.w);
        *(bf16x8*)(As[0] + r * 32 + pA) = t0.v;
    }
    __syncthreads();

#pragma unroll
    for (int t = 0; t < 8; ++t) {
        const int cur = t & 1, nxt = cur ^ 1;
        const int k0  = t * 32;

        float4 a0, a1;
        if (t < 7) {
            // issue next-tile loads FIRST (latency hides under ds_read+MFMA)
            gld_lds16(gB + k0 + 32, lB[nxt]);
            a0 = *(const float4*)(Arow + k0 + 32 + qh * 8 + 0);
            a1 = *(const float4*)(Arow + k0 + 32 + qh * 8 + 4);
        }

        bf16x8 af[4], bfr[2];
#pragma unroll
        for (int ti = 0; ti < 4; ++ti) {
            const int rr = wm + ti * 16 + ml;
            af[ti] = *(const bf16x8*)&As[cur][rr * 32 + ((kq ^ ((rr >> 1) & 3)) << 3)];
        }
#pragma unroll
        for (int tj = 0; tj < 2; ++tj) {
            const int rr = wn + tj * 16 + ml;
            bfr[tj] = *(const bf16x8*)&Bs[cur][rr * 32 + ((kq ^ ((rr >> 1) & 3)) << 3)];
        }
#pragma unroll
        for (int ti = 0; ti < 4; ++ti)
#pragma unroll
            for (int tj = 0; tj < 2; ++tj)
                acc[ti][tj] = __builtin_amdgcn_mfma_f32_16x16x32_bf16(af[ti], bfr[tj], acc[ti][tj], 0, 0, 0);

        if (t < 7) {
            union { bf16x8 v; unsigned u[4]; } t0;
            t0.u[0] = cvt_pk_bf16(a0.x, a0.y); t0.u[1] = cvt_pk_bf16(a0.z, a0.w);
            t0.u[2] = cvt_pk_bf16(a1.x, a1.y); t0.u[3] = cvt_pk_bf16(a1.z, a1.w);
            *(bf16x8*)(As[nxt] + r * 32 + pA) = t0.v;
        }
        __syncthreads();
    }

    // C/D layout: col = lane&15, row = (lane>>4)*4 + reg
#pragma unroll
    for (int tj = 0; tj < 2; ++tj) {
        const int gn = n0 + wn + tj * 16 + ml;
#pragma unroll
        for (int ti = 0; ti < 4; ++ti) {
#pragma unroll
            for (int rr = 0; rr < 4; ++rr) {
                const int gmo = m0 + wm + ti * 16 + kq * 4 + rr;
                if (gmo >= MQ) continue;
                const float v = acc[ti][tj][rr];
                if (isv) {
                    // head-major: vws[h][token][c], h = gn>>5, c = gn&31
                    vws[(size_t)(gn >> 5) * HSTRIDE + (size_t)gmo * 32 + (gn & 31)] =
                        f2bf(v + b_val[gn]);
                } else {
                    if (gn < 192)      offs[(size_t)gmo * 192 + gn]        = v + b_off[gn];
                    else if (gn < 288) lgts[(size_t)gmo * 96 + (gn - 192)] = v + b_attn[gn - 192];
                }
            }
        }
    }
}

// ---------------- output projection: 512 thr (8 waves), 2-phase dbuf, both operands glds ----------------
__global__ __launch_bounds__(512) void ogemm_kernel(const short* __restrict__ A,
                                                    const short* __restrict__ Wt,
                                                    const float* __restrict__ bias,
                                                    float* __restrict__ C)
{
    // XCD-locality remap: both N-tiles of one M-tile on the same XCD
    const int e = (blockIdx.x & 7) * 52 + (blockIdx.x >> 3);
    if (e >= 412) return;
    const int m0 = (e >> 1) * 128;
    const int n0 = (e & 1) * 128;

    __shared__ short As[2][128 * 32];
    __shared__ short Bs[2][128 * 32];

    const int tid  = threadIdx.x;
    const int r    = tid >> 2;          // row 0..127
    const int kqs  = (tid & 3) ^ ((r >> 1) & 3);
    const short* gA = A  + (size_t)(m0 + r) * 256 + kqs * 8;
    const short* gB = Wt + (size_t)(n0 + r) * 256 + kqs * 8;
    short* lA[2] = { As[0] + tid * 8, As[1] + tid * 8 };
    short* lB[2] = { Bs[0] + tid * 8, Bs[1] + tid * 8 };
    const bool aok = (m0 + r) < MQ;

    const int lane = tid & 63;
    const int wave = tid >> 6;
    const int wm   = (wave & 1) * 64;
    const int wn   = (wave >> 1) * 32;
    const int ml   = lane & 15;
    const int kq   = lane >> 4;

    f32x4 acc[4][2] = {};

    // prologue: stage t=0 into buf 0
    if (aok) gld_lds16(gA, lA[0]);
    gld_lds16(gB, lB[0]);
    __syncthreads();

#pragma unroll
    for (int t = 0; t < 8; ++t) {
        const int cur = t & 1, nxt = cur ^ 1;
        const int k0  = t * 32;

        if (t < 7) {
            if (aok) gld_lds16(gA + k0 + 32, lA[nxt]);
            gld_lds16(gB + k0 + 32, lB[nxt]);
        }

        bf16x8 af[4], bfr[2];
#pragma unroll
        for (int ti = 0; ti < 4; ++ti) {
            const int rr = wm + ti * 16 + ml;
            af[ti] = *(const bf16x8*)&As[cur][rr * 32 + ((kq ^ ((rr >> 1) & 3)) << 3)];
        }
#pragma unroll
        for (int tj = 0; tj < 2; ++tj) {
            const int rr = wn + tj * 16 + ml;
            bfr[tj] = *(const bf16x8*)&Bs[cur][rr * 32 + ((kq ^ ((rr >> 1) & 3)) << 3)];
        }
#pragma unroll
        for (int ti = 0; ti < 4; ++ti)
#pragma unroll
            for (int tj = 0; tj < 2; ++tj)
                acc[ti][tj] = __builtin_amdgcn_mfma_f32_16x16x32_bf16(af[ti], bfr[tj], acc[ti][tj], 0, 0, 0);

        __syncthreads();
    }

#pragma unroll
    for (int tj = 0; tj < 2; ++tj) {
        const int gn = n0 + wn + tj * 16 + ml;
        const float bb = bias[gn];
#pragma unroll
        for (int ti = 0; ti < 4; ++ti) {
#pragma unroll
            for (int rr = 0; rr < 4; ++rr) {
                const int gm = m0 + wm + ti * 16 + kq * 4 + rr;
                if (gm >= MQ) continue;
                C[(size_t)gm * 256 + gn] = acc[ti][tj][rr] + bb;
            }
        }
    }
}

// packed dual-FMA accumulate: acc[d] += {lo,hi of dword d} * w  (4x v_pk_fma_f32)
__device__ __forceinline__ void pk_acc(f32x2 (&acc)[4], uint4 u, float w) {
    f32x2 w2 = {w, w};
    unsigned ud[4] = {u.x, u.y, u.z, u.w};
#pragma unroll
    for (int d = 0; d < 4; ++d) {
        f32x2 v2;
        v2.x = __uint_as_float(ud[d] << 16);
        v2.y = __uint_as_float(ud[d] & 0xFFFF0000u);
        asm("v_pk_fma_f32 %0, %1, %2, %0" : "+v"(acc[d]) : "v"(v2), "v"(w2));
    }
}

// ---------------- sampling: 4 q/block, 128 thr (14.3KB LDS -> ~11 blocks/CU, ~22 waves/CU);
// head-major vws gathers; batch-split XCD swizzle; one-ahead pipeline ----
__global__ __launch_bounds__(128) void sample_kernel(const short* __restrict__ vws,
                                                     const float* __restrict__ offs,
                                                     const float* __restrict__ logits,
                                                     const float* __restrict__ refp,
                                                     short* __restrict__ mid)
{
    // 6568 blocks: tiles of 4 queries. Tiles 0..3281 (batch 0 + boundary) -> XCD 0-3,
    // tiles 3282..6562 (batch 1) -> XCD 4-7.
    const int bid = blockIdx.x;
    const int xcd = bid & 7, pos = bid >> 3;
    int g;
    if (xcd < 4) { g = pos * 4 + xcd;              if (g >= 3282) return; }
    else         { g = 3282 + pos * 4 + (xcd - 4); if (g >= 6563) return; }
    const int q0  = g * 4;
    const int tid = threadIdx.x;

    __shared__ float  s_lg[4][96];
    __shared__ float  s_ref[4][6];
    __shared__ float  s_stat[4][NH][2];
    __shared__ float4 s_w[4][96];   // slot = sample*8 + head
    __shared__ int4   s_i[4][96];   // pre-scaled (token*32) element offsets (head-major)

    // Phase A: stage logits + refs
    for (int idx = tid; idx < 384; idx += 128) {
        const int qq = idx / 96, s = idx % 96;
        const int q = q0 + qq;
        if (q < MQ) s_lg[qq][s] = logits[(size_t)q * 96 + s];
    }
    if (tid < 24) {
        const int qq = tid / 6, j = tid % 6;
        const int q = q0 + qq;
        if (q < MQ) s_ref[qq][j] = refp[(size_t)q * 6 + j];
    }
    __syncthreads();

    // Phase B: per-head softmax stats
    if (tid < 32) {
        const int qq = tid >> 3, h = tid & 7;
        if (q0 + qq < MQ) {
            float mx = -1e30f;
#pragma unroll
            for (int i = 0; i < 12; ++i) mx = fmaxf(mx, s_lg[qq][h * 12 + i]);
            float ssum = 0.f;
#pragma unroll
            for (int i = 0; i < 12; ++i) ssum += __expf(s_lg[qq][h * 12 + i] - mx);
            s_stat[qq][h][0] = mx;
            s_stat[qq][h][1] = 1.f / ssum;
        }
    }
    __syncthreads();

    // Phase C: folded corner weights + pre-scaled token offsets (linear slot writes).
    for (int idx = tid; idx < 384; idx += 128) {
        const int qq = idx / 96, slot = idx % 96;
        const int q  = q0 + qq;
        if (q >= MQ) continue;
        const int b  = q / NQ;
        const int h  = slot & 7, i = slot >> 3;   // slot = i*8 + h
        const int l  = i >> 2, p = i & 3;

        const int Hs[3] = {100, 50, 25};
        const int Wz[3] = {100, 50, 25};
        const int Lo[3] = {0, 10000, 12500};
        const int Wl = Wz[l], Hl = Hs[l];
        const float fW = (float)Wl, fH = (float)Hl;

        const float aw = __expf(s_lg[qq][h * 12 + i] - s_stat[qq][h][0]) * s_stat[qq][h][1];

        const int oi = (((h * NL) + l) * NP + p) * 2;
        const float2 offp = *(const float2*)(offs + (size_t)q * 192 + oi);
        const float rx = s_ref[qq][l * 2 + 0];
        const float ry = s_ref[qq][l * 2 + 1];

        const float x = (rx + offp.x / fW) * fW - 0.5f;
        const float y = (ry + offp.y / fH) * fH - 0.5f;
        const float x0f = floorf(x), y0f = floorf(y);
        const int   x0 = (int)x0f,  y0 = (int)y0f;
        const float wx1 = x - x0f, wy1 = y - y0f;
        const float wx0 = 1.f - wx1, wy0 = 1.f - wy1;

        const bool xin0 = (x0 >= 0) && (x0 < Wl);
        const bool xin1 = (x0 + 1 >= 0) && (x0 + 1 < Wl);
        const bool yin0 = (y0 >= 0) && (y0 < Hl);
        const bool yin1 = (y0 + 1 >= 0) && (y0 + 1 < Hl);

        const int cx0 = min(max(x0, 0), Wl - 1);
        const int cx1 = min(max(x0 + 1, 0), Wl - 1);
        const int cy0 = min(max(y0, 0), Hl - 1);
        const int cy1 = min(max(y0 + 1, 0), Hl - 1);

        const int base = b * NTOK + Lo[l];
        int4 idxv;
        idxv.x = (base + cy0 * Wl + cx0) << 5;   // pre-scale by 32 (head-major token stride)
        idxv.y = (base + cy0 * Wl + cx1) << 5;
        idxv.z = (base + cy1 * Wl + cx0) << 5;
        idxv.w = (base + cy1 * Wl + cx1) << 5;

        float4 w;
        w.x = (xin0 && yin0) ? aw * wx0 * wy0 : 0.f;
        w.y = (xin1 && yin0) ? aw * wx1 * wy0 : 0.f;
        w.z = (xin0 && yin1) ? aw * wx0 * wy1 : 0.f;
        w.w = (xin1 && yin1) ? aw * wx1 * wy1 : 0.f;

        s_w[qq][slot] = w;
        s_i[qq][slot] = idxv;
    }
    __syncthreads();

    // Phase D: gather-FMA, 32 threads/query, 8 bf16 channels/lane (16B loads), pk_fma,
    // one-ahead prefetch; gathers hit head-major planes (x-pairs share cache lines).
    {
        const int qq = tid >> 5;
        const int q  = q0 + qq;
        if (q < MQ) {
            const int r   = tid & 31;
            const int h   = r >> 2;
            const int c8  = (r & 3) * 8;
            const int chb = h * HDIM + c8;        // mid layout unchanged
            const short* base = vws + (size_t)h * HSTRIDE + c8;

            float4 w_ = s_w[qq][h];          // s=0, slot=h
            int4  id_ = s_i[qq][h];
            uint4 a_ = *(const uint4*)(base + id_.x);
            uint4 b_ = *(const uint4*)(base + id_.y);
            uint4 c_ = *(const uint4*)(base + id_.z);
            uint4 d_ = *(const uint4*)(base + id_.w);

            f32x2 acc[4] = {};
#pragma unroll
            for (int s = 0; s < 12; ++s) {
                const float4 w = w_;
                const uint4 ua = a_, ub = b_, uc = c_, ud = d_;
                if (s < 11) {
                    const int slot = (s + 1) * 8 + h;
                    w_  = s_w[qq][slot];
                    id_ = s_i[qq][slot];
                    a_ = *(const uint4*)(base + id_.x);
                    b_ = *(const uint4*)(base + id_.y);
                    c_ = *(const uint4*)(base + id_.z);
                    d_ = *(const uint4*)(base + id_.w);
                }
                pk_acc(acc, ua, w.x);
                pk_acc(acc, ub, w.y);
                pk_acc(acc, uc, w.z);
                pk_acc(acc, ud, w.w);
            }
            uint4 o;
            o.x = cvt_pk_bf16(acc[0].x, acc[0].y);
            o.y = cvt_pk_bf16(acc[1].x, acc[1].y);
            o.z = cvt_pk_bf16(acc[2].x, acc[2].y);
            o.w = cvt_pk_bf16(acc[3].x, acc[3].y);
            *(uint4*)(mid + (size_t)q * DM + chb) = o;
        }
    }
}

// ---------------------------------------------------------------------------------------------
extern "C" void kernel_launch(void* const* d_in, const int* in_sizes, int n_in,
                              void* d_out, int out_size, void* d_ws, size_t ws_size,
                              hipStream_t stream)
{
    const float* query  = (const float*)d_in[0];
    const float* refp   = (const float*)d_in[1];
    const float* v0     = (const float*)d_in[2];
    const float* v1     = (const float*)d_in[3];
    const float* v2     = (const float*)d_in[4];
    const float* W_val  = (const float*)d_in[5];
    const float* b_val  = (const float*)d_in[6];
    const float* W_off  = (const float*)d_in[7];
    const float* b_off  = (const float*)d_in[8];
    const float* W_attn = (const float*)d_in[9];
    const float* b_attn = (const float*)d_in[10];
    const float* W_out  = (const float*)d_in[11];
    const float* b_out  = (const float*)d_in[12];
    float* out = (float*)d_out;

    float* ws   = (float*)d_ws;
    float* offs = ws;                                    // MQ*192 f32
    float* lgts = offs + (size_t)MQ * 192;               // MQ*96 f32
    short* vws  = (short*)(lgts + (size_t)MQ * 96);      // MQ*256 bf16, head-major planes
    short* mid  = vws + (size_t)MQ * DM;                 // MQ*256 bf16
    short* Wt   = mid + (size_t)MQ * DM;                 // 229376 bf16
    short* Wt_val = Wt;                                  // rows 0..255
    short* Wt_off = Wt + 65536;                          // 384 rows: off|attn|pad
    short* Wt_out = Wt + 163840;                         // 256 rows

    // 1. weights -> bf16 transposed (+ zero pad)
    wprep_kernel<<<1280, 256, 0, stream>>>(W_val, W_off, W_attn, W_out, Wt);
    // 2. fused vproj + offs/logits (XCD-swizzled, 512 thr, 2-phase dbuf, head-major vws out)
    gemm5_kernel<<<1032, 512, 0, stream>>>(query, v0, v1, v2, Wt_val, Wt_off,
                                           b_val, b_off, b_attn, vws, offs, lgts);
    // 3. softmax + bilinear sampling (4 q/block, 128 thr, batch-split XCD swizzle)
    sample_kernel<<<6568, 128, 0, stream>>>(vws, offs, lgts, refp, mid);
    // 4. output projection (512 thr, 2-phase dbuf)
    ogemm_kernel<<<416, 512, 0, stream>>>(mid, Wt_out, b_out, out);
}

// Round 11
// 200.722 us; speedup vs baseline: 1.0473x; 1.0473x over previous
//
#include <hip/hip_runtime.h>
#include <hip/hip_bf16.h>
#include <math.h>

#define BATCH 2
#define NQ    13125
#define MQ    26250   // BATCH*NQ
#define DM    256
#define NH    8
#define HDIM  32
#define NL    3
#define NP    4
#define NTOK  13125   // value tokens per batch (10000+2500+625)
#define HSTRIDE (MQ * 32)   // per-head plane in head-major vws (tokens x 32ch)

typedef __attribute__((ext_vector_type(8))) short bf16x8;
typedef __attribute__((ext_vector_type(4))) float f32x4;
typedef __attribute__((ext_vector_type(2))) float f32x2;

__device__ __forceinline__ short f2bf(float f) {
    unsigned u = __float_as_uint(f);
    unsigned r = (u + 0x7FFFu + ((u >> 16) & 1u)) >> 16;
    return (short)r;
}
__device__ __forceinline__ float bf2f(unsigned short u) {
    return __uint_as_float((unsigned)u << 16);
}
// hardware packed f32->bf16 (RNE, identical numerics to f2bf)
__device__ __forceinline__ unsigned cvt_pk_bf16(float lo, float hi) {
    unsigned r;
    asm("v_cvt_pk_bf16_f32 %0, %1, %2" : "=v"(r) : "v"(lo), "v"(hi));
    return r;
}

// async global->LDS, 16B per lane. LDS dest must be wave-uniform base + lane*16.
__device__ __forceinline__ void gld_lds16(const short* g, short* l) {
    __builtin_amdgcn_global_load_lds(
        (const __attribute__((address_space(1))) unsigned int*)g,
        (__attribute__((address_space(3))) unsigned int*)l, 16, 0, 0);
}

// ---------------- weight prep: Wt[n][k] bf16 <- W[k][n] fp32, + zero pad ----------------
// Wt layout: Wt_val rows 0..255 | Wt_off 384 rows (off 0..191, attn 192..287, pad 288..383) | Wt_out
__global__ __launch_bounds__(256) void wprep_kernel(const float* __restrict__ Wv,
                                                    const float* __restrict__ Wo,
                                                    const float* __restrict__ Wa,
                                                    const float* __restrict__ Wu,
                                                    short* __restrict__ Wt)
{
    const int bid = blockIdx.x;
    const int w  = bid >> 8;
    const int Ns[5]   = {256, 192, 96, 256, 96};
    const int Offs[5] = {0, 65536, 114688, 163840, 139264};
    const int N = Ns[w];
    const int flat = (bid & 255) * 256 + threadIdx.x;
    const int n = flat >> 8, k = flat & 255;
    if (n >= N) return;
    if (w == 4) { Wt[139264 + n * 256 + k] = 0; return; }
    const float* W = (w == 0) ? Wv : ((w == 1) ? Wo : ((w == 2) ? Wa : Wu));
    Wt[Offs[w] + n * 256 + k] = f2bf(W[k * N + n]);
}

// ---------------- fused vproj + offs/logits GEMM: 512 thr (8 waves), 2-phase dbuf ----------------
// vws output HEAD-MAJOR: vws[h][token][32ch] (token stride 64B).
__global__ __launch_bounds__(512) void gemm5_kernel(const float* __restrict__ query,
                                                    const float* __restrict__ v0,
                                                    const float* __restrict__ v1,
                                                    const float* __restrict__ v2,
                                                    const short* __restrict__ Wt_val,
                                                    const short* __restrict__ Wt_off,
                                                    const float* __restrict__ b_val,
                                                    const float* __restrict__ b_off,
                                                    const float* __restrict__ b_attn,
                                                    short* __restrict__ vws,
                                                    float* __restrict__ offs,
                                                    float* __restrict__ lgts)
{
    // XCD-locality remap: e = (bid%8)*129 + bid/8 ; (gx, y) = (e/5, e%5)
    const int e = (blockIdx.x & 7) * 129 + (blockIdx.x >> 3);
    if (e >= 1030) return;
    const int y  = e % 5;
    const int m0 = (e / 5) * 128;

    __shared__ short As[2][128 * 32];
    __shared__ short Bs[2][128 * 32];

    const int tid  = threadIdx.x;
    const bool isv = (y < 2);
    const short* Wt = isv ? Wt_val : Wt_off;
    const int n0 = isv ? y * 128 : (y - 2) * 128;

    // ---- per-thread staging coords: row = tid>>2 (0..127), k-quarter qh = tid&3 ----
    const int r  = tid >> 2;
    const int qh = tid & 3;
    const int gm = m0 + r;
    const int gmc = (gm < MQ) ? gm : (MQ - 1);   // clamp: OOB rows read finite garbage
    const float* Arow;
    if (isv) {
        const int b  = gmc / NTOK;
        const int rr = gmc % NTOK;
        if (rr < 10000)      Arow = v0 + (size_t)(b * 10000 + rr) * 256;
        else if (rr < 12500) Arow = v1 + (size_t)(b * 2500 + rr - 10000) * 256;
        else                 Arow = v2 + (size_t)(b * 625 + rr - 12500) * 256;
    } else {
        Arow = query + (size_t)gmc * 256;
    }
    const int pA = (qh ^ ((r >> 1) & 3)) << 3;   // XOR k-granule swizzle (matches read)

    // ---- B staging (glds): same (row, granule) ownership ----
    const int kqs = qh ^ ((r >> 1) & 3);
    const short* gB = Wt + (size_t)(n0 + r) * 256 + kqs * 8;
    short* lB[2] = { Bs[0] + tid * 8, Bs[1] + tid * 8 };

    const int lane = tid & 63;
    const int wave = tid >> 6;
    const int wm   = (wave & 1) * 64;
    const int wn   = (wave >> 1) * 32;
    const int ml   = lane & 15;
    const int kq   = lane >> 4;

    f32x4 acc[4][2] = {};

    // ---- prologue: stage t=0 into buf 0 ----
    {
        gld_lds16(gB, lB[0]);
        const float4 a0 = *(const float4*)(Arow + qh * 8 + 0);
        const float4 a1 = *(const float4*)(Arow + qh * 8 + 4);
        union { bf16x8 v; unsigned u[4]; } t0;
        t0.u[0] = cvt_pk_bf16(a0.x, a0.y); t0.u[1] = cvt_pk_bf16(a0.z, a0.w);
        t0.u[2] = cvt_pk_bf16(a1.x, a1.y); t0.u[3] = cvt_pk_bf16(a1.z, a1.w);
        *(bf16x8*)(As[0] + r * 32 + pA) = t0.v;
    }
    __syncthreads();

#pragma unroll
    for (int t = 0; t < 8; ++t) {
        const int cur = t & 1, nxt = cur ^ 1;
        const int k0  = t * 32;

        float4 a0, a1;
        if (t < 7) {
            // issue next-tile loads FIRST (latency hides under ds_read+MFMA)
            gld_lds16(gB + k0 + 32, lB[nxt]);
            a0 = *(const float4*)(Arow + k0 + 32 + qh * 8 + 0);
            a1 = *(const float4*)(Arow + k0 + 32 + qh * 8 + 4);
        }

        bf16x8 af[4], bfr[2];
#pragma unroll
        for (int ti = 0; ti < 4; ++ti) {
            const int rr = wm + ti * 16 + ml;
            af[ti] = *(const bf16x8*)&As[cur][rr * 32 + ((kq ^ ((rr >> 1) & 3)) << 3)];
        }
#pragma unroll
        for (int tj = 0; tj < 2; ++tj) {
            const int rr = wn + tj * 16 + ml;
            bfr[tj] = *(const bf16x8*)&Bs[cur][rr * 32 + ((kq ^ ((rr >> 1) & 3)) << 3)];
        }
#pragma unroll
        for (int ti = 0; ti < 4; ++ti)
#pragma unroll
            for (int tj = 0; tj < 2; ++tj)
                acc[ti][tj] = __builtin_amdgcn_mfma_f32_16x16x32_bf16(af[ti], bfr[tj], acc[ti][tj], 0, 0, 0);

        if (t < 7) {
            union { bf16x8 v; unsigned u[4]; } t0;
            t0.u[0] = cvt_pk_bf16(a0.x, a0.y); t0.u[1] = cvt_pk_bf16(a0.z, a0.w);
            t0.u[2] = cvt_pk_bf16(a1.x, a1.y); t0.u[3] = cvt_pk_bf16(a1.z, a1.w);
            *(bf16x8*)(As[nxt] + r * 32 + pA) = t0.v;
        }
        __syncthreads();
    }

    // C/D layout: col = lane&15, row = (lane>>4)*4 + reg
#pragma unroll
    for (int tj = 0; tj < 2; ++tj) {
        const int gn = n0 + wn + tj * 16 + ml;
#pragma unroll
        for (int ti = 0; ti < 4; ++ti) {
#pragma unroll
            for (int rr = 0; rr < 4; ++rr) {
                const int gmo = m0 + wm + ti * 16 + kq * 4 + rr;
                if (gmo >= MQ) continue;
                const float v = acc[ti][tj][rr];
                if (isv) {
                    // head-major: vws[h][token][c], h = gn>>5, c = gn&31
                    vws[(size_t)(gn >> 5) * HSTRIDE + (size_t)gmo * 32 + (gn & 31)] =
                        f2bf(v + b_val[gn]);
                } else {
                    if (gn < 192)      offs[(size_t)gmo * 192 + gn]        = v + b_off[gn];
                    else if (gn < 288) lgts[(size_t)gmo * 96 + (gn - 192)] = v + b_attn[gn - 192];
                }
            }
        }
    }
}

// ---------------- output projection: 512 thr (8 waves), 2-phase dbuf, both operands glds ----------------
__global__ __launch_bounds__(512) void ogemm_kernel(const short* __restrict__ A,
                                                    const short* __restrict__ Wt,
                                                    const float* __restrict__ bias,
                                                    float* __restrict__ C)
{
    // XCD-locality remap: both N-tiles of one M-tile on the same XCD
    const int e = (blockIdx.x & 7) * 52 + (blockIdx.x >> 3);
    if (e >= 412) return;
    const int m0 = (e >> 1) * 128;
    const int n0 = (e & 1) * 128;

    __shared__ short As[2][128 * 32];
    __shared__ short Bs[2][128 * 32];

    const int tid  = threadIdx.x;
    const int r    = tid >> 2;          // row 0..127
    const int kqs  = (tid & 3) ^ ((r >> 1) & 3);
    const short* gA = A  + (size_t)(m0 + r) * 256 + kqs * 8;
    const short* gB = Wt + (size_t)(n0 + r) * 256 + kqs * 8;
    short* lA[2] = { As[0] + tid * 8, As[1] + tid * 8 };
    short* lB[2] = { Bs[0] + tid * 8, Bs[1] + tid * 8 };
    const bool aok = (m0 + r) < MQ;

    const int lane = tid & 63;
    const int wave = tid >> 6;
    const int wm   = (wave & 1) * 64;
    const int wn   = (wave >> 1) * 32;
    const int ml   = lane & 15;
    const int kq   = lane >> 4;

    f32x4 acc[4][2] = {};

    // prologue: stage t=0 into buf 0
    if (aok) gld_lds16(gA, lA[0]);
    gld_lds16(gB, lB[0]);
    __syncthreads();

#pragma unroll
    for (int t = 0; t < 8; ++t) {
        const int cur = t & 1, nxt = cur ^ 1;
        const int k0  = t * 32;

        if (t < 7) {
            if (aok) gld_lds16(gA + k0 + 32, lA[nxt]);
            gld_lds16(gB + k0 + 32, lB[nxt]);
        }

        bf16x8 af[4], bfr[2];
#pragma unroll
        for (int ti = 0; ti < 4; ++ti) {
            const int rr = wm + ti * 16 + ml;
            af[ti] = *(const bf16x8*)&As[cur][rr * 32 + ((kq ^ ((rr >> 1) & 3)) << 3)];
        }
#pragma unroll
        for (int tj = 0; tj < 2; ++tj) {
            const int rr = wn + tj * 16 + ml;
            bfr[tj] = *(const bf16x8*)&Bs[cur][rr * 32 + ((kq ^ ((rr >> 1) & 3)) << 3)];
        }
#pragma unroll
        for (int ti = 0; ti < 4; ++ti)
#pragma unroll
            for (int tj = 0; tj < 2; ++tj)
                acc[ti][tj] = __builtin_amdgcn_mfma_f32_16x16x32_bf16(af[ti], bfr[tj], acc[ti][tj], 0, 0, 0);

        __syncthreads();
    }

#pragma unroll
    for (int tj = 0; tj < 2; ++tj) {
        const int gn = n0 + wn + tj * 16 + ml;
        const float bb = bias[gn];
#pragma unroll
        for (int ti = 0; ti < 4; ++ti) {
#pragma unroll
            for (int rr = 0; rr < 4; ++rr) {
                const int gm = m0 + wm + ti * 16 + kq * 4 + rr;
                if (gm >= MQ) continue;
                C[(size_t)gm * 256 + gn] = acc[ti][tj][rr] + bb;
            }
        }
    }
}

// packed dual-FMA accumulate: acc[d] += {lo,hi of dword d} * w  (4x v_pk_fma_f32)
__device__ __forceinline__ void pk_acc(f32x2 (&acc)[4], uint4 u, float w) {
    f32x2 w2 = {w, w};
    unsigned ud[4] = {u.x, u.y, u.z, u.w};
#pragma unroll
    for (int d = 0; d < 4; ++d) {
        f32x2 v2;
        v2.x = __uint_as_float(ud[d] << 16);
        v2.y = __uint_as_float(ud[d] & 0xFFFF0000u);
        asm("v_pk_fma_f32 %0, %1, %2, %0" : "+v"(acc[d]) : "v"(v2), "v"(w2));
    }
}

// ---------------- sampling: HEAD-PARTITIONED. head = bid&7 = XCD, 32 queries/block, 128 thr.
// Each XCD's gathers hit ONLY its head's 1.68MB vws plane -> L2-resident (4MB/XCD).
// Per-head slices of logits (48B/q) and offs (96B/q contiguous). One-ahead pipeline. ----
__global__ __launch_bounds__(128) void sample_kernel(const short* __restrict__ vws,
                                                     const float* __restrict__ offs,
                                                     const float* __restrict__ logits,
                                                     const float* __restrict__ refp,
                                                     short* __restrict__ mid)
{
    const int bid = blockIdx.x;
    const int h   = bid & 7;          // head == XCD (round-robin dispatch)
    const int q0  = (bid >> 3) * 32;  // 821 query tiles per head
    if (q0 >= MQ) return;
    const int tid = threadIdx.x;

    __shared__ float  s_lg[32][13];   // +1 pad: row stride 13 words, bank-clean
    __shared__ float  s_ref[32][6];
    __shared__ float2 s_stat[32];
    __shared__ float4 s_w[32][13];    // 12 used; stride 52 words -> 2-way max (free)
    __shared__ int4   s_i[32][13];    // pre-scaled (token*32) offsets (head-major)

    // Phase A: stage this head's logit slice + refs
    for (int idx = tid; idx < 384; idx += 128) {
        const int qq = idx / 12, i = idx % 12;
        const int q = q0 + qq;
        if (q < MQ) s_lg[qq][i] = logits[(size_t)q * 96 + h * 12 + i];
    }
    for (int idx = tid; idx < 192; idx += 128) {
        const int qq = idx / 6, j = idx % 6;
        const int q = q0 + qq;
        if (q < MQ) s_ref[qq][j] = refp[(size_t)q * 6 + j];
    }
    __syncthreads();

    // Phase B: per-query softmax stats (12 logits of this head)
    if (tid < 32) {
        const int qq = tid;
        if (q0 + qq < MQ) {
            float mx = -1e30f;
#pragma unroll
            for (int i = 0; i < 12; ++i) mx = fmaxf(mx, s_lg[qq][i]);
            float ssum = 0.f;
#pragma unroll
            for (int i = 0; i < 12; ++i) ssum += __expf(s_lg[qq][i] - mx);
            s_stat[qq].x = mx;
            s_stat[qq].y = 1.f / ssum;
        }
    }
    __syncthreads();

    // Phase C: folded corner weights + pre-scaled token offsets
    for (int idx = tid; idx < 384; idx += 128) {
        const int qq = idx / 12, i = idx % 12;
        const int q  = q0 + qq;
        if (q >= MQ) continue;
        const int b  = q / NQ;
        const int l  = i >> 2, p = i & 3;

        const int Hs[3] = {100, 50, 25};
        const int Wz[3] = {100, 50, 25};
        const int Lo[3] = {0, 10000, 12500};
        const int Wl = Wz[l], Hl = Hs[l];
        const float fW = (float)Wl, fH = (float)Hl;

        const float aw = __expf(s_lg[qq][i] - s_stat[qq].x) * s_stat[qq].y;

        const int oi = h * 24 + l * 8 + p * 2;   // contiguous per-head slice
        const float2 offp = *(const float2*)(offs + (size_t)q * 192 + oi);
        const float rx = s_ref[qq][l * 2 + 0];
        const float ry = s_ref[qq][l * 2 + 1];

        const float x = (rx + offp.x / fW) * fW - 0.5f;
        const float y = (ry + offp.y / fH) * fH - 0.5f;
        const float x0f = floorf(x), y0f = floorf(y);
        const int   x0 = (int)x0f,  y0 = (int)y0f;
        const float wx1 = x - x0f, wy1 = y - y0f;
        const float wx0 = 1.f - wx1, wy0 = 1.f - wy1;

        const bool xin0 = (x0 >= 0) && (x0 < Wl);
        const bool xin1 = (x0 + 1 >= 0) && (x0 + 1 < Wl);
        const bool yin0 = (y0 >= 0) && (y0 < Hl);
        const bool yin1 = (y0 + 1 >= 0) && (y0 + 1 < Hl);

        const int cx0 = min(max(x0, 0), Wl - 1);
        const int cx1 = min(max(x0 + 1, 0), Wl - 1);
        const int cy0 = min(max(y0, 0), Hl - 1);
        const int cy1 = min(max(y0 + 1, 0), Hl - 1);

        const int base = b * NTOK + Lo[l];
        int4 idxv;
        idxv.x = (base + cy0 * Wl + cx0) << 5;   // pre-scale by 32 (head-major token stride)
        idxv.y = (base + cy0 * Wl + cx1) << 5;
        idxv.z = (base + cy1 * Wl + cx0) << 5;
        idxv.w = (base + cy1 * Wl + cx1) << 5;

        float4 w;
        w.x = (xin0 && yin0) ? aw * wx0 * wy0 : 0.f;
        w.y = (xin1 && yin0) ? aw * wx1 * wy0 : 0.f;
        w.z = (xin0 && yin1) ? aw * wx0 * wy1 : 0.f;
        w.w = (xin1 && yin1) ? aw * wx1 * wy1 : 0.f;

        s_w[qq][i] = w;
        s_i[qq][i] = idxv;
    }
    __syncthreads();

    // Phase D: gather-FMA. 4 lanes/query x 8 ch (16B loads), L2-resident plane h,
    // one-ahead prefetch of next sample's weights/ids/gathers.
    {
        const int qq = tid >> 2;
        const int q  = q0 + qq;
        if (q < MQ) {
            const int c8 = (tid & 3) * 8;
            const short* base = vws + (size_t)h * HSTRIDE + c8;

            float4 w_ = s_w[qq][0];
            int4  id_ = s_i[qq][0];
            uint4 a_ = *(const uint4*)(base + id_.x);
            uint4 b_ = *(const uint4*)(base + id_.y);
            uint4 c_ = *(const uint4*)(base + id_.z);
            uint4 d_ = *(const uint4*)(base + id_.w);

            f32x2 acc[4] = {};
#pragma unroll
            for (int s = 0; s < 12; ++s) {
                const float4 w = w_;
                const uint4 ua = a_, ub = b_, uc = c_, ud = d_;
                if (s < 11) {
                    w_  = s_w[qq][s + 1];
                    id_ = s_i[qq][s + 1];
                    a_ = *(const uint4*)(base + id_.x);
                    b_ = *(const uint4*)(base + id_.y);
                    c_ = *(const uint4*)(base + id_.z);
                    d_ = *(const uint4*)(base + id_.w);
                }
                pk_acc(acc, ua, w.x);
                pk_acc(acc, ub, w.y);
                pk_acc(acc, uc, w.z);
                pk_acc(acc, ud, w.w);
            }
            uint4 o;
            o.x = cvt_pk_bf16(acc[0].x, acc[0].y);
            o.y = cvt_pk_bf16(acc[1].x, acc[1].y);
            o.z = cvt_pk_bf16(acc[2].x, acc[2].y);
            o.w = cvt_pk_bf16(acc[3].x, acc[3].y);
            *(uint4*)(mid + (size_t)q * DM + h * HDIM + c8) = o;
        }
    }
}

// ---------------------------------------------------------------------------------------------
extern "C" void kernel_launch(void* const* d_in, const int* in_sizes, int n_in,
                              void* d_out, int out_size, void* d_ws, size_t ws_size,
                              hipStream_t stream)
{
    const float* query  = (const float*)d_in[0];
    const float* refp   = (const float*)d_in[1];
    const float* v0     = (const float*)d_in[2];
    const float* v1     = (const float*)d_in[3];
    const float* v2     = (const float*)d_in[4];
    const float* W_val  = (const float*)d_in[5];
    const float* b_val  = (const float*)d_in[6];
    const float* W_off  = (const float*)d_in[7];
    const float* b_off  = (const float*)d_in[8];
    const float* W_attn = (const float*)d_in[9];
    const float* b_attn = (const float*)d_in[10];
    const float* W_out  = (const float*)d_in[11];
    const float* b_out  = (const float*)d_in[12];
    float* out = (float*)d_out;

    float* ws   = (float*)d_ws;
    float* offs = ws;                                    // MQ*192 f32
    float* lgts = offs + (size_t)MQ * 192;               // MQ*96 f32
    short* vws  = (short*)(lgts + (size_t)MQ * 96);      // MQ*256 bf16, head-major planes
    short* mid  = vws + (size_t)MQ * DM;                 // MQ*256 bf16
    short* Wt   = mid + (size_t)MQ * DM;                 // 229376 bf16
    short* Wt_val = Wt;                                  // rows 0..255
    short* Wt_off = Wt + 65536;                          // 384 rows: off|attn|pad
    short* Wt_out = Wt + 163840;                         // 256 rows

    // 1. weights -> bf16 transposed (+ zero pad)
    wprep_kernel<<<1280, 256, 0, stream>>>(W_val, W_off, W_attn, W_out, Wt);
    // 2. fused vproj + offs/logits (XCD-swizzled, 512 thr, 2-phase dbuf, head-major vws out)
    gemm5_kernel<<<1032, 512, 0, stream>>>(query, v0, v1, v2, Wt_val, Wt_off,
                                           b_val, b_off, b_attn, vws, offs, lgts);
    // 3. softmax + bilinear sampling: head-partitioned, head = XCD (8 x 821 = 6568 blocks)
    sample_kernel<<<6568, 128, 0, stream>>>(vws, offs, lgts, refp, mid);
    // 4. output projection (512 thr, 2-phase dbuf)
    ogemm_kernel<<<416, 512, 0, stream>>>(mid, Wt_out, b_out, out);
}

// Round 12
// 198.952 us; speedup vs baseline: 1.0566x; 1.0089x over previous
//
#include <hip/hip_runtime.h>
#include <hip/hip_bf16.h>
#include <math.h>

#define BATCH 2
#define NQ    13125
#define MQ    26250   // BATCH*NQ
#define DM    256
#define NH    8
#define HDIM  32
#define NL    3
#define NP    4
#define NTOK  13125   // value tokens per batch (10000+2500+625)
#define HSTRIDE (MQ * 32)   // per-head plane in head-major vws (tokens x 32ch)

typedef __attribute__((ext_vector_type(8))) short bf16x8;
typedef __attribute__((ext_vector_type(4))) float f32x4;
typedef __attribute__((ext_vector_type(2))) float f32x2;

__device__ __forceinline__ short f2bf(float f) {
    unsigned u = __float_as_uint(f);
    unsigned r = (u + 0x7FFFu + ((u >> 16) & 1u)) >> 16;
    return (short)r;
}
__device__ __forceinline__ float bf2f(unsigned short u) {
    return __uint_as_float((unsigned)u << 16);
}
// hardware packed f32->bf16 (RNE, identical numerics to f2bf)
__device__ __forceinline__ unsigned cvt_pk_bf16(float lo, float hi) {
    unsigned r;
    asm("v_cvt_pk_bf16_f32 %0, %1, %2" : "=v"(r) : "v"(lo), "v"(hi));
    return r;
}

// async global->LDS, 16B per lane. LDS dest must be wave-uniform base + lane*16.
__device__ __forceinline__ void gld_lds16(const short* g, short* l) {
    __builtin_amdgcn_global_load_lds(
        (const __attribute__((address_space(1))) unsigned int*)g,
        (__attribute__((address_space(3))) unsigned int*)l, 16, 0, 0);
}

__device__ __forceinline__ void fence_barrier_lgkm() {
    asm volatile("s_waitcnt lgkmcnt(0)" ::: "memory");
    __builtin_amdgcn_sched_barrier(0);
    __builtin_amdgcn_s_barrier();
    __builtin_amdgcn_sched_barrier(0);
}

// ---------------- weight prep: Wt[n][k] bf16 <- W[k][n] fp32, + zero pad ----------------
// Wt layout: Wt_val rows 0..255 | Wt_off 384 rows (off 0..191, attn 192..287, pad 288..383) | Wt_out
__global__ __launch_bounds__(256) void wprep_kernel(const float* __restrict__ Wv,
                                                    const float* __restrict__ Wo,
                                                    const float* __restrict__ Wa,
                                                    const float* __restrict__ Wu,
                                                    short* __restrict__ Wt)
{
    const int bid = blockIdx.x;
    const int w  = bid >> 8;
    const int Ns[5]   = {256, 192, 96, 256, 96};
    const int Offs[5] = {0, 65536, 114688, 163840, 139264};
    const int N = Ns[w];
    const int flat = (bid & 255) * 256 + threadIdx.x;
    const int n = flat >> 8, k = flat & 255;
    if (n >= N) return;
    if (w == 4) { Wt[139264 + n * 256 + k] = 0; return; }
    const float* W = (w == 0) ? Wv : ((w == 1) ? Wo : ((w == 2) ? Wa : Wu));
    Wt[Offs[w] + n * 256 + k] = f2bf(W[k * N + n]);
}

// ---------------- fused vproj + offs/logits GEMM: 512 thr, DEPTH-2 counted pipeline ----------------
// Per step t: issue tile t+2 (glds B -> Bs[(t+2)%3], A fp32 -> regs); ds_read+MFMA tile t;
// cvt+ds_write tile t+1 (compiler's auto vmcnt wait covers loads issued a FULL STEP earlier,
// and transitively guarantees B(t+1) glds landed); lgkmcnt(0) + RAW s_barrier (no vmcnt drain).
__global__ __launch_bounds__(512) void gemm5_kernel(const float* __restrict__ query,
                                                    const float* __restrict__ v0,
                                                    const float* __restrict__ v1,
                                                    const float* __restrict__ v2,
                                                    const short* __restrict__ Wt_val,
                                                    const short* __restrict__ Wt_off,
                                                    const float* __restrict__ b_val,
                                                    const float* __restrict__ b_off,
                                                    const float* __restrict__ b_attn,
                                                    short* __restrict__ vws,
                                                    float* __restrict__ offs,
                                                    float* __restrict__ lgts)
{
    // XCD-locality remap: e = (bid%8)*129 + bid/8 ; (gx, y) = (e/5, e%5)
    const int e = (blockIdx.x & 7) * 129 + (blockIdx.x >> 3);
    if (e >= 1030) return;
    const int y  = e % 5;
    const int m0 = (e / 5) * 128;

    __shared__ short As[2][128 * 32];   // 16 KB
    __shared__ short Bs[3][128 * 32];   // 24 KB -> 40 KB total, 4 blocks/CU

    const int tid  = threadIdx.x;
    const bool isv = (y < 2);
    const short* Wt = isv ? Wt_val : Wt_off;
    const int n0 = isv ? y * 128 : (y - 2) * 128;

    // ---- per-thread staging coords: row = tid>>2 (0..127), k-quarter qh = tid&3 ----
    const int r  = tid >> 2;
    const int qh = tid & 3;
    const int gm = m0 + r;
    const int gmc = (gm < MQ) ? gm : (MQ - 1);   // clamp: OOB rows read finite garbage
    const float* Arow;
    if (isv) {
        const int b  = gmc / NTOK;
        const int rr = gmc % NTOK;
        if (rr < 10000)      Arow = v0 + (size_t)(b * 10000 + rr) * 256;
        else if (rr < 12500) Arow = v1 + (size_t)(b * 2500 + rr - 10000) * 256;
        else                 Arow = v2 + (size_t)(b * 625 + rr - 12500) * 256;
    } else {
        Arow = query + (size_t)gmc * 256;
    }
    const int pA = (qh ^ ((r >> 1) & 3)) << 3;   // XOR k-granule swizzle (matches read)

    // ---- B staging (glds): same (row, granule) ownership ----
    const int kqs = qh ^ ((r >> 1) & 3);
    const short* gB = Wt + (size_t)(n0 + r) * 256 + kqs * 8;

    const int lane = tid & 63;
    const int wave = tid >> 6;
    const int wm   = (wave & 1) * 64;
    const int wn   = (wave >> 1) * 32;
    const int ml   = lane & 15;
    const int kq   = lane >> 4;

    // Two A register sets: set S holds tile T with T%2 == S
    float4 s0a, s0b, s1a, s1b;
#define LOAD_SET0(T) { s0a = *(const float4*)(Arow + (T)*32 + qh*8 + 0); \
                       s0b = *(const float4*)(Arow + (T)*32 + qh*8 + 4); }
#define LOAD_SET1(T) { s1a = *(const float4*)(Arow + (T)*32 + qh*8 + 0); \
                       s1b = *(const float4*)(Arow + (T)*32 + qh*8 + 4); }
#define CVT_WRITE0(DST) { union { bf16x8 v; unsigned u[4]; } t0;          \
        t0.u[0] = cvt_pk_bf16(s0a.x, s0a.y); t0.u[1] = cvt_pk_bf16(s0a.z, s0a.w); \
        t0.u[2] = cvt_pk_bf16(s0b.x, s0b.y); t0.u[3] = cvt_pk_bf16(s0b.z, s0b.w); \
        *(bf16x8*)((DST) + r * 32 + pA) = t0.v; }
#define CVT_WRITE1(DST) { union { bf16x8 v; unsigned u[4]; } t0;          \
        t0.u[0] = cvt_pk_bf16(s1a.x, s1a.y); t0.u[1] = cvt_pk_bf16(s1a.z, s1a.w); \
        t0.u[2] = cvt_pk_bf16(s1b.x, s1b.y); t0.u[3] = cvt_pk_bf16(s1b.z, s1b.w); \
        *(bf16x8*)((DST) + r * 32 + pA) = t0.v; }

    f32x4 acc[4][2] = {};

    // ---- prologue: tiles 0,1 in flight; tile0 staged to LDS ----
    gld_lds16(gB + 0,  Bs[0] + tid * 8);
    LOAD_SET0(0);
    gld_lds16(gB + 32, Bs[1] + tid * 8);
    LOAD_SET1(1);
    CVT_WRITE0(As[0]);              // auto vmcnt wait: set0 loads -> B0 (older) landed too
    fence_barrier_lgkm();

#pragma unroll
    for (int t = 0; t < 8; ++t) {
        // 1. issue tile t+2 (targets Bs[(t-1)%3], safe: step t-1 reads completed pre-barrier)
        if (t <= 5) {
            gld_lds16(gB + (t + 2) * 32, Bs[(t + 2) % 3] + tid * 8);
            if ((t & 1) == 0) LOAD_SET0(t + 2) else LOAD_SET1(t + 2)
        }

        // 2. ds_read + MFMA tile t
        bf16x8 af[4], bfr[2];
#pragma unroll
        for (int ti = 0; ti < 4; ++ti) {
            const int rr = wm + ti * 16 + ml;
            af[ti] = *(const bf16x8*)&As[t & 1][rr * 32 + ((kq ^ ((rr >> 1) & 3)) << 3)];
        }
#pragma unroll
        for (int tj = 0; tj < 2; ++tj) {
            const int rr = wn + tj * 16 + ml;
            bfr[tj] = *(const bf16x8*)&Bs[t % 3][rr * 32 + ((kq ^ ((rr >> 1) & 3)) << 3)];
        }
#pragma unroll
        for (int ti = 0; ti < 4; ++ti)
#pragma unroll
            for (int tj = 0; tj < 2; ++tj)
                acc[ti][tj] = __builtin_amdgcn_mfma_f32_16x16x32_bf16(af[ti], bfr[tj], acc[ti][tj], 0, 0, 0);

        // 3. cvt + ds_write tile t+1 (loads issued at step t-1: a full step of latency cover)
        if (t < 7) {
            if (((t + 1) & 1) == 0) CVT_WRITE0(As[(t + 1) & 1]) else CVT_WRITE1(As[(t + 1) & 1])
        }

        // 4. fence + RAW barrier (no vmcnt(0) drain)
        fence_barrier_lgkm();
    }
#undef LOAD_SET0
#undef LOAD_SET1
#undef CVT_WRITE0
#undef CVT_WRITE1

    // C/D layout: col = lane&15, row = (lane>>4)*4 + reg
#pragma unroll
    for (int tj = 0; tj < 2; ++tj) {
        const int gn = n0 + wn + tj * 16 + ml;
#pragma unroll
        for (int ti = 0; ti < 4; ++ti) {
#pragma unroll
            for (int rr = 0; rr < 4; ++rr) {
                const int gmo = m0 + wm + ti * 16 + kq * 4 + rr;
                if (gmo >= MQ) continue;
                const float v = acc[ti][tj][rr];
                if (isv) {
                    // head-major: vws[h][token][c], h = gn>>5, c = gn&31
                    vws[(size_t)(gn >> 5) * HSTRIDE + (size_t)gmo * 32 + (gn & 31)] =
                        f2bf(v + b_val[gn]);
                } else {
                    if (gn < 192)      offs[(size_t)gmo * 192 + gn]        = v + b_off[gn];
                    else if (gn < 288) lgts[(size_t)gmo * 96 + (gn - 192)] = v + b_attn[gn - 192];
                }
            }
        }
    }
}

// ---------------- output projection: 512 thr, DEPTH-2 counted-vmcnt pipeline, pure glds ----------------
// Uniform 2 glds/thread/step (A row clamped, not predicated, so vmcnt counts are wave-uniform).
// Step t: issue tile t+2; read+MFMA tile t; s_waitcnt vmcnt(2) (tile t+1 landed); raw barrier.
__global__ __launch_bounds__(512) void ogemm_kernel(const short* __restrict__ A,
                                                    const short* __restrict__ Wt,
                                                    const float* __restrict__ bias,
                                                    float* __restrict__ C)
{
    // XCD-locality remap: both N-tiles of one M-tile on the same XCD
    const int e = (blockIdx.x & 7) * 52 + (blockIdx.x >> 3);
    if (e >= 412) return;
    const int m0 = (e >> 1) * 128;
    const int n0 = (e & 1) * 128;

    __shared__ short As[3][128 * 32];
    __shared__ short Bs[3][128 * 32];   // 48 KB total, 3 blocks/CU

    const int tid  = threadIdx.x;
    const int r    = tid >> 2;          // row 0..127
    const int kqs  = (tid & 3) ^ ((r >> 1) & 3);
    const int gmr  = m0 + r;
    const int gmrc = (gmr < MQ) ? gmr : (MQ - 1);   // clamp for uniform glds counts
    const short* gA = A  + (size_t)gmrc * 256 + kqs * 8;
    const short* gB = Wt + (size_t)(n0 + r) * 256 + kqs * 8;

    const int lane = tid & 63;
    const int wave = tid >> 6;
    const int wm   = (wave & 1) * 64;
    const int wn   = (wave >> 1) * 32;
    const int ml   = lane & 15;
    const int kq   = lane >> 4;

    f32x4 acc[4][2] = {};

    // prologue: tiles 0,1 in flight (4 ops); wait tile0 (2 newest outstanding); barrier
    gld_lds16(gA + 0,  As[0] + tid * 8);
    gld_lds16(gB + 0,  Bs[0] + tid * 8);
    gld_lds16(gA + 32, As[1] + tid * 8);
    gld_lds16(gB + 32, Bs[1] + tid * 8);
    asm volatile("s_waitcnt vmcnt(2)" ::: "memory");
    __builtin_amdgcn_sched_barrier(0);
    __builtin_amdgcn_s_barrier();
    __builtin_amdgcn_sched_barrier(0);

#pragma unroll
    for (int t = 0; t < 8; ++t) {
        if (t <= 5) {
            gld_lds16(gA + (t + 2) * 32, As[(t + 2) % 3] + tid * 8);
            gld_lds16(gB + (t + 2) * 32, Bs[(t + 2) % 3] + tid * 8);
        }

        bf16x8 af[4], bfr[2];
#pragma unroll
        for (int ti = 0; ti < 4; ++ti) {
            const int rr = wm + ti * 16 + ml;
            af[ti] = *(const bf16x8*)&As[t % 3][rr * 32 + ((kq ^ ((rr >> 1) & 3)) << 3)];
        }
#pragma unroll
        for (int tj = 0; tj < 2; ++tj) {
            const int rr = wn + tj * 16 + ml;
            bfr[tj] = *(const bf16x8*)&Bs[t % 3][rr * 32 + ((kq ^ ((rr >> 1) & 3)) << 3)];
        }
#pragma unroll
        for (int ti = 0; ti < 4; ++ti)
#pragma unroll
            for (int tj = 0; tj < 2; ++tj)
                acc[ti][tj] = __builtin_amdgcn_mfma_f32_16x16x32_bf16(af[ti], bfr[tj], acc[ti][tj], 0, 0, 0);

        if (t < 7) {
            // ensure tile t+1 landed (outstanding: t+1(2) + t+2(2) when t<=5; only t+1 at t=6)
            if (t <= 5) asm volatile("s_waitcnt vmcnt(2)" ::: "memory");
            else        asm volatile("s_waitcnt vmcnt(0)" ::: "memory");
            __builtin_amdgcn_sched_barrier(0);
            __builtin_amdgcn_s_barrier();
            __builtin_amdgcn_sched_barrier(0);
        }
    }

#pragma unroll
    for (int tj = 0; tj < 2; ++tj) {
        const int gn = n0 + wn + tj * 16 + ml;
        const float bb = bias[gn];
#pragma unroll
        for (int ti = 0; ti < 4; ++ti) {
#pragma unroll
            for (int rr = 0; rr < 4; ++rr) {
                const int gm = m0 + wm + ti * 16 + kq * 4 + rr;
                if (gm >= MQ) continue;
                C[(size_t)gm * 256 + gn] = acc[ti][tj][rr] + bb;
            }
        }
    }
}

// packed dual-FMA accumulate: acc[d] += {lo,hi of dword d} * w  (4x v_pk_fma_f32)
__device__ __forceinline__ void pk_acc(f32x2 (&acc)[4], uint4 u, float w) {
    f32x2 w2 = {w, w};
    unsigned ud[4] = {u.x, u.y, u.z, u.w};
#pragma unroll
    for (int d = 0; d < 4; ++d) {
        f32x2 v2;
        v2.x = __uint_as_float(ud[d] << 16);
        v2.y = __uint_as_float(ud[d] & 0xFFFF0000u);
        asm("v_pk_fma_f32 %0, %1, %2, %0" : "+v"(acc[d]) : "v"(v2), "v"(w2));
    }
}

// ---------------- sampling (R11-proven, UNTOUCHED): head-partitioned, head = XCD ----------------
__global__ __launch_bounds__(128) void sample_kernel(const short* __restrict__ vws,
                                                     const float* __restrict__ offs,
                                                     const float* __restrict__ logits,
                                                     const float* __restrict__ refp,
                                                     short* __restrict__ mid)
{
    const int bid = blockIdx.x;
    const int h   = bid & 7;          // head == XCD (round-robin dispatch)
    const int q0  = (bid >> 3) * 32;  // 821 query tiles per head
    if (q0 >= MQ) return;
    const int tid = threadIdx.x;

    __shared__ float  s_lg[32][13];   // +1 pad: row stride 13 words, bank-clean
    __shared__ float  s_ref[32][6];
    __shared__ float2 s_stat[32];
    __shared__ float4 s_w[32][13];    // 12 used; stride 52 words -> 2-way max (free)
    __shared__ int4   s_i[32][13];    // pre-scaled (token*32) offsets (head-major)

    // Phase A: stage this head's logit slice + refs
    for (int idx = tid; idx < 384; idx += 128) {
        const int qq = idx / 12, i = idx % 12;
        const int q = q0 + qq;
        if (q < MQ) s_lg[qq][i] = logits[(size_t)q * 96 + h * 12 + i];
    }
    for (int idx = tid; idx < 192; idx += 128) {
        const int qq = idx / 6, j = idx % 6;
        const int q = q0 + qq;
        if (q < MQ) s_ref[qq][j] = refp[(size_t)q * 6 + j];
    }
    __syncthreads();

    // Phase B: per-query softmax stats (12 logits of this head)
    if (tid < 32) {
        const int qq = tid;
        if (q0 + qq < MQ) {
            float mx = -1e30f;
#pragma unroll
            for (int i = 0; i < 12; ++i) mx = fmaxf(mx, s_lg[qq][i]);
            float ssum = 0.f;
#pragma unroll
            for (int i = 0; i < 12; ++i) ssum += __expf(s_lg[qq][i] - mx);
            s_stat[qq].x = mx;
            s_stat[qq].y = 1.f / ssum;
        }
    }
    __syncthreads();

    // Phase C: folded corner weights + pre-scaled token offsets
    for (int idx = tid; idx < 384; idx += 128) {
        const int qq = idx / 12, i = idx % 12;
        const int q  = q0 + qq;
        if (q >= MQ) continue;
        const int b  = q / NQ;
        const int l  = i >> 2, p = i & 3;

        const int Hs[3] = {100, 50, 25};
        const int Wz[3] = {100, 50, 25};
        const int Lo[3] = {0, 10000, 12500};
        const int Wl = Wz[l], Hl = Hs[l];
        const float fW = (float)Wl, fH = (float)Hl;

        const float aw = __expf(s_lg[qq][i] - s_stat[qq].x) * s_stat[qq].y;

        const int oi = h * 24 + l * 8 + p * 2;   // contiguous per-head slice
        const float2 offp = *(const float2*)(offs + (size_t)q * 192 + oi);
        const float rx = s_ref[qq][l * 2 + 0];
        const float ry = s_ref[qq][l * 2 + 1];

        const float x = (rx + offp.x / fW) * fW - 0.5f;
        const float y = (ry + offp.y / fH) * fH - 0.5f;
        const float x0f = floorf(x), y0f = floorf(y);
        const int   x0 = (int)x0f,  y0 = (int)y0f;
        const float wx1 = x - x0f, wy1 = y - y0f;
        const float wx0 = 1.f - wx1, wy0 = 1.f - wy1;

        const bool xin0 = (x0 >= 0) && (x0 < Wl);
        const bool xin1 = (x0 + 1 >= 0) && (x0 + 1 < Wl);
        const bool yin0 = (y0 >= 0) && (y0 < Hl);
        const bool yin1 = (y0 + 1 >= 0) && (y0 + 1 < Hl);

        const int cx0 = min(max(x0, 0), Wl - 1);
        const int cx1 = min(max(x0 + 1, 0), Wl - 1);
        const int cy0 = min(max(y0, 0), Hl - 1);
        const int cy1 = min(max(y0 + 1, 0), Hl - 1);

        const int base = b * NTOK + Lo[l];
        int4 idxv;
        idxv.x = (base + cy0 * Wl + cx0) << 5;   // pre-scale by 32 (head-major token stride)
        idxv.y = (base + cy0 * Wl + cx1) << 5;
        idxv.z = (base + cy1 * Wl + cx0) << 5;
        idxv.w = (base + cy1 * Wl + cx1) << 5;

        float4 w;
        w.x = (xin0 && yin0) ? aw * wx0 * wy0 : 0.f;
        w.y = (xin1 && yin0) ? aw * wx1 * wy0 : 0.f;
        w.z = (xin0 && yin1) ? aw * wx0 * wy1 : 0.f;
        w.w = (xin1 && yin1) ? aw * wx1 * wy1 : 0.f;

        s_w[qq][i] = w;
        s_i[qq][i] = idxv;
    }
    __syncthreads();

    // Phase D: gather-FMA. 4 lanes/query x 8 ch (16B loads), L2-resident plane h,
    // one-ahead prefetch of next sample's weights/ids/gathers.
    {
        const int qq = tid >> 2;
        const int q  = q0 + qq;
        if (q < MQ) {
            const int c8 = (tid & 3) * 8;
            const short* base = vws + (size_t)h * HSTRIDE + c8;

            float4 w_ = s_w[qq][0];
            int4  id_ = s_i[qq][0];
            uint4 a_ = *(const uint4*)(base + id_.x);
            uint4 b_ = *(const uint4*)(base + id_.y);
            uint4 c_ = *(const uint4*)(base + id_.z);
            uint4 d_ = *(const uint4*)(base + id_.w);

            f32x2 acc[4] = {};
#pragma unroll
            for (int s = 0; s < 12; ++s) {
                const float4 w = w_;
                const uint4 ua = a_, ub = b_, uc = c_, ud = d_;
                if (s < 11) {
                    w_  = s_w[qq][s + 1];
                    id_ = s_i[qq][s + 1];
                    a_ = *(const uint4*)(base + id_.x);
                    b_ = *(const uint4*)(base + id_.y);
                    c_ = *(const uint4*)(base + id_.z);
                    d_ = *(const uint4*)(base + id_.w);
                }
                pk_acc(acc, ua, w.x);
                pk_acc(acc, ub, w.y);
                pk_acc(acc, uc, w.z);
                pk_acc(acc, ud, w.w);
            }
            uint4 o;
            o.x = cvt_pk_bf16(acc[0].x, acc[0].y);
            o.y = cvt_pk_bf16(acc[1].x, acc[1].y);
            o.z = cvt_pk_bf16(acc[2].x, acc[2].y);
            o.w = cvt_pk_bf16(acc[3].x, acc[3].y);
            *(uint4*)(mid + (size_t)q * DM + h * HDIM + c8) = o;
        }
    }
}

// ---------------------------------------------------------------------------------------------
extern "C" void kernel_launch(void* const* d_in, const int* in_sizes, int n_in,
                              void* d_out, int out_size, void* d_ws, size_t ws_size,
                              hipStream_t stream)
{
    const float* query  = (const float*)d_in[0];
    const float* refp   = (const float*)d_in[1];
    const float* v0     = (const float*)d_in[2];
    const float* v1     = (const float*)d_in[3];
    const float* v2     = (const float*)d_in[4];
    const float* W_val  = (const float*)d_in[5];
    const float* b_val  = (const float*)d_in[6];
    const float* W_off  = (const float*)d_in[7];
    const float* b_off  = (const float*)d_in[8];
    const float* W_attn = (const float*)d_in[9];
    const float* b_attn = (const float*)d_in[10];
    const float* W_out  = (const float*)d_in[11];
    const float* b_out  = (const float*)d_in[12];
    float* out = (float*)d_out;

    float* ws   = (float*)d_ws;
    float* offs = ws;                                    // MQ*192 f32
    float* lgts = offs + (size_t)MQ * 192;               // MQ*96 f32
    short* vws  = (short*)(lgts + (size_t)MQ * 96);      // MQ*256 bf16, head-major planes
    short* mid  = vws + (size_t)MQ * DM;                 // MQ*256 bf16
    short* Wt   = mid + (size_t)MQ * DM;                 // 229376 bf16
    short* Wt_val = Wt;                                  // rows 0..255
    short* Wt_off = Wt + 65536;                          // 384 rows: off|attn|pad
    short* Wt_out = Wt + 163840;                         // 256 rows

    // 1. weights -> bf16 transposed (+ zero pad)
    wprep_kernel<<<1280, 256, 0, stream>>>(W_val, W_off, W_attn, W_out, Wt);
    // 2. fused vproj + offs/logits (XCD-swizzled, 512 thr, depth-2 counted pipeline)
    gemm5_kernel<<<1032, 512, 0, stream>>>(query, v0, v1, v2, Wt_val, Wt_off,
                                           b_val, b_off, b_attn, vws, offs, lgts);
    // 3. softmax + bilinear sampling: head-partitioned, head = XCD (8 x 821 = 6568 blocks)
    sample_kernel<<<6568, 128, 0, stream>>>(vws, offs, lgts, refp, mid);
    // 4. output projection (512 thr, depth-2 counted pipeline)
    ogemm_kernel<<<416, 512, 0, stream>>>(mid, Wt_out, b_out, out);
}